// Round 14
// baseline (117.821 us; speedup 1.0000x reference)
//
#include <hip/hip_runtime.h>
#include <math.h>

#define NU 100000
#define NI 50000
#define DK 256      // DU == DI
#define EN 128      // E
#define BB 8192
#define TT 24

typedef short short8 __attribute__((ext_vector_type(8)));
typedef float f32x4  __attribute__((ext_vector_type(4)));

// ---- d_ws layout (bytes) ----
#define WPACK_SHORTS 114688
#define WP_OFF     0
#define OWNER_OFF  229376                 // 100000 ints
#define NTAB_OFF   629376                 // 50000*128 bf16 = 12.8 MB
#define NPART_OFF  13429376               // 8192*128 f32  = 4 MB

// wpack element offsets (bf16 shorts, all [N][K] k-contiguous)
#define OFF_IWT   0        // 128x256
#define OFF_UWT   32768    // 128x256
#define OFF_AW1UT 65536    // 128x128 (aW1 rows 0..127   -> neigh part)
#define OFF_AW1LT 81920    // 128x128 (aW1 rows 128..255 -> node part)
#define OFF_AW2T  98304    // 128x128

#define NBLK_NEIGH 782     // ceil(NI/64)
#define NBLK_NF    128     // BB/64
#define NBLK_PACK  448     // WPACK_SHORTS/256
#define GGA 4              // batch rows per attn group
#define NGRP 2             // groups per attn block (software pipeline depth)
#define ATTN_BLKS (BB / (GGA * NGRP))   // 1024

__device__ __forceinline__ unsigned short f2b(float x) {
    unsigned int u = __float_as_uint(x);
    u = (u + 0x7FFFu + ((u >> 16) & 1u)) >> 16;   // RNE, finite inputs
    return (unsigned short)u;
}
__device__ __forceinline__ float b2f(unsigned short v) {
    return __uint_as_float(((unsigned int)v) << 16);
}
__device__ __forceinline__ unsigned int cvtpk_bf16(float lo, float hi) {
    unsigned int r;
    asm("v_cvt_pk_bf16_f32 %0, %1, %2" : "=v"(r) : "v"(lo), "v"(hi));
    return r;
}

#define MFMA(a, b, c) __builtin_amdgcn_mfma_f32_16x16x32_bf16((a), (b), (c), 0, 0, 0)
#define LDROW(buf, stride, row, k) \
    (*reinterpret_cast<const short8*>(reinterpret_cast<const char*>(buf) + (row) * (stride) + (k) * 2))

// ---- K1 (tiny): pack weights + owner reset ----
__global__ __launch_bounds__(256)
void prep_kernel(const int* __restrict__ nodes,
                 const float* __restrict__ uW, const float* __restrict__ iW,
                 const float* __restrict__ aW1, const float* __restrict__ aW2,
                 short* __restrict__ wp, int* __restrict__ owner)
{
    if (blockIdx.x < NBLK_PACK) {
        int i = blockIdx.x * 256 + threadIdx.x;
        float v;
        if (i < 32768)      { int j = i;         int n = j >> 8, k = j & 255; v = iW[k * EN + n]; }
        else if (i < 65536) { int j = i - 32768; int n = j >> 8, k = j & 255; v = uW[k * EN + n]; }
        else if (i < 81920) { int j = i - 65536; int n = j >> 7, k = j & 127; v = aW1[k * EN + n]; }
        else if (i < 98304) { int j = i - 81920; int n = j >> 7, k = j & 127; v = aW1[(128 + k) * EN + n]; }
        else                { int j = i - 98304; int n = j >> 7, k = j & 127; v = aW2[k * EN + n]; }
        wp[i] = (short)f2b(v);
    } else {
        int b = (blockIdx.x - NBLK_PACK) * 256 + threadIdx.x;
        if (b < BB) owner[nodes[b]] = -1;
    }
}

// ---- K2: union kernel: neighs table | nf/npart (+owner max) ; tail-zero of out_embed ----
__global__ __launch_bounds__(256, 4)
void embed_kernel(const int* __restrict__ nodes,
                  const float* __restrict__ u_weight, const float* __restrict__ i_weight,
                  const float* __restrict__ ub, const float* __restrict__ ib,
                  const float* __restrict__ ab1,
                  const short* __restrict__ wp, int* __restrict__ owner,
                  short* __restrict__ ntab, float* __restrict__ out_nf,
                  float* __restrict__ npart, float* __restrict__ out_embed)
{
    __shared__ __align__(16) char smem[33792];
    __shared__ int sNd[64];

    const int tid = threadIdx.x;
    const int l = tid & 63, lr = l & 15, lq = l >> 4, n0 = (tid >> 6) * 32;
    const int kA = lq * 8, nc0 = n0 + lr, nc1 = n0 + 16 + lr;

    if (blockIdx.x < NBLK_NEIGH) {
        const int r0 = blockIdx.x * 64;
        const int nrows = (NI - r0 < 64) ? (NI - r0) : 64;

        for (int task = tid; task < 64 * 32; task += 256) {
            int row = task >> 5, c = task & 31;
            if (row < nrows) {
                const float* src = i_weight + (size_t)(r0 + row) * DK + c * 8;
                float4 f0 = *(const float4*)src;
                float4 f1 = *(const float4*)(src + 4);
                short8 o;
                o[0]=f2b(f0.x); o[1]=f2b(f0.y); o[2]=f2b(f0.z); o[3]=f2b(f0.w);
                o[4]=f2b(f1.x); o[5]=f2b(f1.y); o[6]=f2b(f1.z); o[7]=f2b(f1.w);
                *reinterpret_cast<short8*>(smem + row * 528 + c * 16) = o;
            }
        }
        __syncthreads();

        const short* iWt = wp + OFF_IWT;
        f32x4 acc[4][2];
        #pragma unroll
        for (int m = 0; m < 4; ++m) { acc[m][0] = {0.f,0.f,0.f,0.f}; acc[m][1] = {0.f,0.f,0.f,0.f}; }
        #pragma unroll
        for (int ks = 0; ks < 8; ++ks) {
            int k = ks * 32 + kA;
            short8 w0 = *reinterpret_cast<const short8*>(iWt + nc0 * DK + k);
            short8 w1 = *reinterpret_cast<const short8*>(iWt + nc1 * DK + k);
            #pragma unroll
            for (int m = 0; m < 4; ++m) {
                short8 a = LDROW(smem, 528, m * 16 + lr, k);
                acc[m][0] = MFMA(a, w0, acc[m][0]);
                acc[m][1] = MFMA(a, w1, acc[m][1]);
            }
        }
        __syncthreads();
        {
            float ib0 = ib[nc0], ib1 = ib[nc1];
            #pragma unroll
            for (int m = 0; m < 4; ++m)
                #pragma unroll
                for (int nt = 0; nt < 2; ++nt) {
                    int n = nt ? nc1 : nc0;
                    float bv = nt ? ib1 : ib0;
                    #pragma unroll
                    for (int r = 0; r < 4; ++r) {
                        int row = m * 16 + lq * 4 + r;
                        *reinterpret_cast<short*>(smem + row * 264 + n * 2)
                            = (short)f2b(acc[m][nt][r] + bv);
                    }
                }
        }
        __syncthreads();
        for (int g = tid; g < nrows * 16; g += 256) {
            int row = g >> 4, s = g & 15;
            short8 v = *reinterpret_cast<const short8*>(smem + row * 264 + s * 16);
            *reinterpret_cast<short8*>(ntab + (size_t)(r0 + row) * EN + s * 8) = v;
        }
    } else {
        const int bblk = blockIdx.x - NBLK_NEIGH;
        const int r0 = bblk * 64;
        {
            int bq = bblk * 256 + tid;
            if (bq < BB) atomicMax(&owner[nodes[bq]], bq);
        }
        if (tid < 64) sNd[tid] = nodes[r0 + tid];
        __syncthreads();

        for (int task = tid; task < 64 * 32; task += 256) {
            int row = task >> 5, c = task & 31;
            const float* src = u_weight + (size_t)sNd[row] * DK + c * 8;
            float4 f0 = *(const float4*)src;
            float4 f1 = *(const float4*)(src + 4);
            short8 o;
            o[0]=f2b(f0.x); o[1]=f2b(f0.y); o[2]=f2b(f0.z); o[3]=f2b(f0.w);
            o[4]=f2b(f1.x); o[5]=f2b(f1.y); o[6]=f2b(f1.z); o[7]=f2b(f1.w);
            *reinterpret_cast<short8*>(smem + row * 528 + c * 16) = o;
        }
        __syncthreads();

        const short* uWt   = wp + OFF_UWT;
        const short* aW1Lt = wp + OFF_AW1LT;

        f32x4 acc[4][2];
        #pragma unroll
        for (int m = 0; m < 4; ++m) { acc[m][0] = {0.f,0.f,0.f,0.f}; acc[m][1] = {0.f,0.f,0.f,0.f}; }
        #pragma unroll
        for (int ks = 0; ks < 8; ++ks) {
            int k = ks * 32 + kA;
            short8 w0 = *reinterpret_cast<const short8*>(uWt + nc0 * DK + k);
            short8 w1 = *reinterpret_cast<const short8*>(uWt + nc1 * DK + k);
            #pragma unroll
            for (int m = 0; m < 4; ++m) {
                short8 a = LDROW(smem, 528, m * 16 + lr, k);
                acc[m][0] = MFMA(a, w0, acc[m][0]);
                acc[m][1] = MFMA(a, w1, acc[m][1]);
            }
        }
        __syncthreads();
        {
            float b0v = ub[nc0], b1v = ub[nc1];
            #pragma unroll
            for (int m = 0; m < 4; ++m)
                #pragma unroll
                for (int nt = 0; nt < 2; ++nt) {
                    int n = nt ? nc1 : nc0;
                    float bv = nt ? b1v : b0v;
                    #pragma unroll
                    for (int r = 0; r < 4; ++r) {
                        int row = m * 16 + lq * 4 + r;
                        float v = acc[m][nt][r] + bv;
                        out_nf[(size_t)(r0 + row) * EN + n] = v;
                        *reinterpret_cast<short*>(smem + row * 272 + n * 2) = (short)f2b(v);
                    }
                }
        }
        __syncthreads();

        f32x4 ap[4][2];
        #pragma unroll
        for (int m = 0; m < 4; ++m) { ap[m][0] = {0.f,0.f,0.f,0.f}; ap[m][1] = {0.f,0.f,0.f,0.f}; }
        #pragma unroll
        for (int ks = 0; ks < 4; ++ks) {
            int k = ks * 32 + kA;
            short8 w0 = *reinterpret_cast<const short8*>(aW1Lt + nc0 * EN + k);
            short8 w1 = *reinterpret_cast<const short8*>(aW1Lt + nc1 * EN + k);
            #pragma unroll
            for (int m = 0; m < 4; ++m) {
                short8 a = LDROW(smem, 272, m * 16 + lr, k);
                ap[m][0] = MFMA(a, w0, ap[m][0]);
                ap[m][1] = MFMA(a, w1, ap[m][1]);
            }
        }
        {
            float b0v = ab1[nc0], b1v = ab1[nc1];
            #pragma unroll
            for (int m = 0; m < 4; ++m)
                #pragma unroll
                for (int nt = 0; nt < 2; ++nt) {
                    int n = nt ? nc1 : nc0;
                    float bv = nt ? b1v : b0v;
                    #pragma unroll
                    for (int r = 0; r < 4; ++r) {
                        int row = m * 16 + lq * 4 + r;
                        npart[(size_t)(r0 + row) * EN + n] = ap[m][nt][r] + bv;
                    }
                }
        }
    }

    {
        float4* embed4 = (float4*)out_embed;
        const int n16 = NU * EN / 4;
        const int gsz = (NBLK_NEIGH + NBLK_NF) * 256;
        float4 z = {0.f, 0.f, 0.f, 0.f};
        for (int i = blockIdx.x * 256 + tid; i < n16; i += gsz) embed4[i] = z;
    }
}

// ---- compute one GGA-group given gathered rows in sbuf + keep regs (R13-verified math) ----
__device__ __forceinline__ void attn_compute(
    int b0, int l, int w, int lr, int lq, int nc0, int nc1, int kA,
    char* sbuf, float (*sLogP)[96],
    short8 k0, short8 k1, short8 k2, short8 k3, short8 k4, short8 k5,
    const float* __restrict__ npart, const float* __restrict__ ab2,
    const float* __restrict__ aW3, const float* __restrict__ ab3,
    const short* __restrict__ aW1Ut, const short* __restrict__ aW2t,
    const int* __restrict__ nodes, const int* __restrict__ owner,
    float* __restrict__ out_embed)
{
    // ---- h1 MFMA = neighs @ aW1U (reads sbuf) ----
    f32x4 acc[6][2];
    #pragma unroll
    for (int m = 0; m < 6; ++m) { acc[m][0] = {0.f,0.f,0.f,0.f}; acc[m][1] = {0.f,0.f,0.f,0.f}; }
    #pragma unroll
    for (int ks = 0; ks < 4; ++ks) {
        int k = ks * 32 + kA;
        short8 w0 = *reinterpret_cast<const short8*>(aW1Ut + nc0 * EN + k);
        short8 w1 = *reinterpret_cast<const short8*>(aW1Ut + nc1 * EN + k);
        #pragma unroll
        for (int m = 0; m < 6; ++m) {
            short8 a = LDROW(sbuf, 264, m * 16 + lr, k);
            acc[m][0] = MFMA(a, w0, acc[m][0]);
            acc[m][1] = MFMA(a, w1, acc[m][1]);
        }
    }
    __syncthreads();   // all A-reads of sbuf complete before overlay

    // ---- h1 epilogue: relu(acc + npart) -> bf16, overlay INTO sbuf ----
    #pragma unroll
    for (int m = 0; m < 6; ++m) {
        int g = (m == 0) ? 0 : (m == 1) ? ((lq < 2) ? 0 : 1)
              : (m == 2) ? 1 : (m == 3) ? 2 : (m == 4) ? ((lq < 2) ? 2 : 3) : 3;
        #pragma unroll
        for (int nt = 0; nt < 2; ++nt) {
            int n = nt ? nc1 : nc0;
            float np = npart[(size_t)(b0 + g) * EN + n];
            float v0 = fmaxf(acc[m][nt][0] + np, 0.f);
            float v1 = fmaxf(acc[m][nt][1] + np, 0.f);
            float v2 = fmaxf(acc[m][nt][2] + np, 0.f);
            float v3 = fmaxf(acc[m][nt][3] + np, 0.f);
            unsigned int p01 = cvtpk_bf16(v0, v1);
            unsigned int p23 = cvtpk_bf16(v2, v3);
            char* base = sbuf + (m * 16 + lq * 4) * 264 + (nt ? nc1 : nc0) * 2;
            *reinterpret_cast<short*>(base)       = (short)(p01 & 0xFFFF);
            *reinterpret_cast<short*>(base + 264) = (short)(p01 >> 16);
            *reinterpret_cast<short*>(base + 528) = (short)(p23 & 0xFFFF);
            *reinterpret_cast<short*>(base + 792) = (short)(p23 >> 16);
        }
    }
    __syncthreads();

    // ---- h2 = relu(h1 @ aW2 + ab2); logits reduced in-register ----
    #pragma unroll
    for (int m = 0; m < 6; ++m) { acc[m][0] = {0.f,0.f,0.f,0.f}; acc[m][1] = {0.f,0.f,0.f,0.f}; }
    #pragma unroll
    for (int ks = 0; ks < 4; ++ks) {
        int k = ks * 32 + kA;
        short8 w0 = *reinterpret_cast<const short8*>(aW2t + nc0 * EN + k);
        short8 w1 = *reinterpret_cast<const short8*>(aW2t + nc1 * EN + k);
        #pragma unroll
        for (int m = 0; m < 6; ++m) {
            short8 a = LDROW(sbuf, 264, m * 16 + lr, k);
            acc[m][0] = MFMA(a, w0, acc[m][0]);
            acc[m][1] = MFMA(a, w1, acc[m][1]);
        }
    }
    {
        float b0v = ab2[nc0], b1v = ab2[nc1];
        float w3a = aW3[nc0], w3b = aW3[nc1];
        #pragma unroll
        for (int m = 0; m < 6; ++m) {
            float lp[4];
            #pragma unroll
            for (int r = 0; r < 4; ++r) {
                float v0 = fmaxf(acc[m][0][r] + b0v, 0.f);
                float v1 = fmaxf(acc[m][1][r] + b1v, 0.f);
                lp[r] = v0 * w3a + v1 * w3b;
            }
            #pragma unroll
            for (int r = 0; r < 4; ++r) {
                float v = lp[r];
                v += __shfl_xor(v, 1, 16);
                v += __shfl_xor(v, 2, 16);
                v += __shfl_xor(v, 4, 16);
                v += __shfl_xor(v, 8, 16);
                if (lr == 0) sLogP[w][m * 16 + lq * 4 + r] = v;
            }
        }
    }
    __syncthreads();

    // ---- per-wave softmax over T=24 ----
    float lg = -1e30f;
    if (l < TT)
        lg = sLogP[0][w * 24 + l] + sLogP[1][w * 24 + l]
           + sLogP[2][w * 24 + l] + sLogP[3][w * 24 + l] + ab3[0];
    float mx = lg;
    #pragma unroll
    for (int d = 32; d > 0; d >>= 1) mx = fmaxf(mx, __shfl_xor(mx, d, 64));
    float p = (l < TT) ? __expf(lg - mx) : 0.f;
    float s = p;
    #pragma unroll
    for (int d = 32; d > 0; d >>= 1) s += __shfl_xor(s, d, 64);
    float att = p / s;

    // ---- agg from keep registers; butterfly; scatter ----
    {
        float part[8] = {0.f,0.f,0.f,0.f,0.f,0.f,0.f,0.f};
        const int q = l >> 4;
        #pragma unroll
        for (int j = 0; j < 6; ++j) {
            float wt = __shfl(att, j * 4 + q, 64);
            short8 v = (j == 0) ? k0 : (j == 1) ? k1 : (j == 2) ? k2
                     : (j == 3) ? k3 : (j == 4) ? k4 : k5;
            #pragma unroll
            for (int e = 0; e < 8; ++e)
                part[e] += wt * b2f((unsigned short)v[e]);
        }
        #pragma unroll
        for (int e = 0; e < 8; ++e) {
            part[e] += __shfl_xor(part[e], 16, 64);
            part[e] += __shfl_xor(part[e], 32, 64);
        }
        int node = nodes[b0 + w];
        if (l < 16 && owner[node] == b0 + w) {
            float4 o0 = {part[0], part[1], part[2], part[3]};
            float4 o1 = {part[4], part[5], part[6], part[7]};
            float4* dst = reinterpret_cast<float4*>(out_embed + (size_t)node * EN + (l & 15) * 8);
            dst[0] = o0;
            dst[1] = o1;
        }
    }
}

// ---- K3: attn, 2 groups per block; group1's gather is in flight during group0's compute ----
__global__ __launch_bounds__(256, 3)
void attn_kernel(const int* __restrict__ nodes, const int* __restrict__ neigh_idx,
                 const float* __restrict__ ab2, const float* __restrict__ aW3,
                 const float* __restrict__ ab3, const short* __restrict__ wp,
                 const short* __restrict__ ntab, const float* __restrict__ npart,
                 const int* __restrict__ owner, float* __restrict__ out_embed)
{
    __shared__ __align__(16) char sbuf[96 * 264];  // 25344 B: neighs / h1 overlay (single buffer)
    __shared__ float sLogP[4][96];                 //  1536 B  => 26880 B total

    const int tid = threadIdx.x;
    const int l   = tid & 63, w = tid >> 6;
    const int lr  = l & 15, lq = l >> 4;
    const int n0  = w * 32;
    const int kA  = lq * 8, nc0 = n0 + lr, nc1 = n0 + 16 + lr;
    const int s   = l & 15, q = l >> 4;

    const short* aW1Ut = wp + OFF_AW1UT;
    const short* aW2t  = wp + OFF_AW2T;

    const int b0a = blockIdx.x * GGA;                    // group 0
    const int b0b = (blockIdx.x + ATTN_BLKS) * GGA;      // group 1

#define GLOAD(dst, bb, j) { \
        int idx_ = neigh_idx[((bb) + w) * TT + (j) * 4 + q]; \
        dst = *reinterpret_cast<const short8*>(ntab + (size_t)idx_ * EN + s * 8); }

    // ---- gather group0 into regs + sbuf ----
    short8 k0, k1, k2, k3, k4, k5;
    GLOAD(k0, b0a, 0) GLOAD(k1, b0a, 1) GLOAD(k2, b0a, 2)
    GLOAD(k3, b0a, 3) GLOAD(k4, b0a, 4) GLOAD(k5, b0a, 5)
    {
        char* base = sbuf + (w * 24 + q) * 264 + s * 16;
        *reinterpret_cast<short8*>(base)            = k0;
        *reinterpret_cast<short8*>(base + 4 * 264)  = k1;
        *reinterpret_cast<short8*>(base + 8 * 264)  = k2;
        *reinterpret_cast<short8*>(base + 12 * 264) = k3;
        *reinterpret_cast<short8*>(base + 16 * 264) = k4;
        *reinterpret_cast<short8*>(base + 20 * 264) = k5;
    }
    __syncthreads();

    // ---- issue group1's gather NOW (in flight during group0's compute) ----
    short8 t0, t1, t2, t3, t4, t5;
    GLOAD(t0, b0b, 0) GLOAD(t1, b0b, 1) GLOAD(t2, b0b, 2)
    GLOAD(t3, b0b, 3) GLOAD(t4, b0b, 4) GLOAD(t5, b0b, 5)

    // ---- compute group0 ----
    attn_compute(b0a, l, w, lr, lq, nc0, nc1, kA, sbuf, sLogP,
                 k0, k1, k2, k3, k4, k5,
                 npart, ab2, aW3, ab3, aW1Ut, aW2t, nodes, owner, out_embed);
    __syncthreads();   // all group0 sbuf/sLogP reads complete

    // ---- write staged group1 rows to sbuf ----
    {
        char* base = sbuf + (w * 24 + q) * 264 + s * 16;
        *reinterpret_cast<short8*>(base)            = t0;
        *reinterpret_cast<short8*>(base + 4 * 264)  = t1;
        *reinterpret_cast<short8*>(base + 8 * 264)  = t2;
        *reinterpret_cast<short8*>(base + 12 * 264) = t3;
        *reinterpret_cast<short8*>(base + 16 * 264) = t4;
        *reinterpret_cast<short8*>(base + 20 * 264) = t5;
    }
    __syncthreads();

    // ---- compute group1 ----
    attn_compute(b0b, l, w, lr, lq, nc0, nc1, kA, sbuf, sLogP,
                 t0, t1, t2, t3, t4, t5,
                 npart, ab2, aW3, ab3, aW1Ut, aW2t, nodes, owner, out_embed);
#undef GLOAD
}

extern "C" void kernel_launch(void* const* d_in, const int* in_sizes, int n_in,
                              void* d_out, int out_size, void* d_ws, size_t ws_size,
                              hipStream_t stream) {
    const int*   nodes     = (const int*)d_in[0];
    const int*   neigh_idx = (const int*)d_in[1];
    const float* u_weight  = (const float*)d_in[2];
    const float* i_weight  = (const float*)d_in[3];
    const float* uW  = (const float*)d_in[4];
    const float* ub  = (const float*)d_in[5];
    const float* iW  = (const float*)d_in[6];
    const float* ib  = (const float*)d_in[7];
    const float* aW1 = (const float*)d_in[8];
    const float* ab1 = (const float*)d_in[9];
    const float* aW2 = (const float*)d_in[10];
    const float* ab2 = (const float*)d_in[11];
    const float* aW3 = (const float*)d_in[12];
    const float* ab3 = (const float*)d_in[13];

    float* out_nf    = (float*)d_out;
    float* out_embed = out_nf + (size_t)BB * EN;

    char*  ws    = (char*)d_ws;
    short* wpack = (short*)(ws + WP_OFF);
    int*   owner = (int*)(ws + OWNER_OFF);
    short* ntab  = (short*)(ws + NTAB_OFF);
    float* npart = (float*)(ws + NPART_OFF);

    prep_kernel<<<NBLK_PACK + 32, 256, 0, stream>>>(nodes, uW, iW, aW1, aW2, wpack, owner);
    embed_kernel<<<NBLK_NEIGH + NBLK_NF, 256, 0, stream>>>(
        nodes, u_weight, i_weight, ub, ib, ab1, wpack, owner, ntab, out_nf, npart, out_embed);
    attn_kernel<<<ATTN_BLKS, 256, 0, stream>>>(nodes, neigh_idx, ab2, aW3, ab3,
                                               wpack, ntab, npart, owner, out_embed);
}

// Round 15
// 78.215 us; speedup vs baseline: 1.5064x; 1.5064x over previous
//
#include <hip/hip_runtime.h>
#include <math.h>

#define NU 100000
#define NI 50000
#define DK 256      // DU == DI
#define EN 128      // E
#define BB 8192
#define TT 24

typedef short short8 __attribute__((ext_vector_type(8)));
typedef float f32x4  __attribute__((ext_vector_type(4)));

// ---- d_ws layout (bytes) ----
#define WPACK_SHORTS 114688
#define WP_OFF     0
#define OWNER_OFF  229376                 // 100000 ints
#define NTAB_OFF   629376                 // 50000*128 bf16 = 12.8 MB
#define NPART_OFF  13429376               // 8192*128 f32  = 4 MB

// wpack element offsets (bf16 shorts, all [N][K] k-contiguous)
#define OFF_IWT   0        // 128x256
#define OFF_UWT   32768    // 128x256
#define OFF_AW1UT 65536    // 128x128 (aW1 rows 0..127   -> neigh part)
#define OFF_AW1LT 81920    // 128x128 (aW1 rows 128..255 -> node part)
#define OFF_AW2T  98304    // 128x128

#define NBLK_NEIGH 782     // ceil(NI/64)
#define NBLK_NF    128     // BB/64
#define NBLK_PACK  448     // WPACK_SHORTS/256
#define GGA 4              // batch rows per attn block
#define ATTN_BLKS  (BB / GGA)

__device__ __forceinline__ unsigned short f2b(float x) {
    unsigned int u = __float_as_uint(x);
    u = (u + 0x7FFFu + ((u >> 16) & 1u)) >> 16;   // RNE, finite inputs
    return (unsigned short)u;
}
__device__ __forceinline__ float b2f(unsigned short v) {
    return __uint_as_float(((unsigned int)v) << 16);
}
__device__ __forceinline__ unsigned int cvtpk_bf16(float lo, float hi) {
    unsigned int r;
    asm("v_cvt_pk_bf16_f32 %0, %1, %2" : "=v"(r) : "v"(lo), "v"(hi));
    return r;
}
// direct global->LDS, 16 B per lane; lds base must be wave-uniform, dest = base + lane*16
__device__ __forceinline__ void gload_lds16(const void* g, void* lds) {
    __builtin_amdgcn_global_load_lds(
        (const __attribute__((address_space(1))) unsigned int*)g,
        (__attribute__((address_space(3))) unsigned int*)lds, 16, 0, 0);
}

#define MFMA(a, b, c) __builtin_amdgcn_mfma_f32_16x16x32_bf16((a), (b), (c), 0, 0, 0)
#define LDROW(buf, stride, row, k) \
    (*reinterpret_cast<const short8*>(reinterpret_cast<const char*>(buf) + (row) * (stride) + (k) * 2))

// ---- K1 (tiny): pack weights + owner reset ----
__global__ __launch_bounds__(256)
void prep_kernel(const int* __restrict__ nodes,
                 const float* __restrict__ uW, const float* __restrict__ iW,
                 const float* __restrict__ aW1, const float* __restrict__ aW2,
                 short* __restrict__ wp, int* __restrict__ owner)
{
    if (blockIdx.x < NBLK_PACK) {
        int i = blockIdx.x * 256 + threadIdx.x;
        float v;
        if (i < 32768)      { int j = i;         int n = j >> 8, k = j & 255; v = iW[k * EN + n]; }
        else if (i < 65536) { int j = i - 32768; int n = j >> 8, k = j & 255; v = uW[k * EN + n]; }
        else if (i < 81920) { int j = i - 65536; int n = j >> 7, k = j & 127; v = aW1[k * EN + n]; }
        else if (i < 98304) { int j = i - 81920; int n = j >> 7, k = j & 127; v = aW1[(128 + k) * EN + n]; }
        else                { int j = i - 98304; int n = j >> 7, k = j & 127; v = aW2[k * EN + n]; }
        wp[i] = (short)f2b(v);
    } else {
        int b = (blockIdx.x - NBLK_PACK) * 256 + threadIdx.x;
        if (b < BB) owner[nodes[b]] = -1;
    }
}

// ---- K2: union kernel: neighs table | nf/npart (+owner max) ; tail-zero of out_embed ----
__global__ __launch_bounds__(256, 4)
void embed_kernel(const int* __restrict__ nodes,
                  const float* __restrict__ u_weight, const float* __restrict__ i_weight,
                  const float* __restrict__ ub, const float* __restrict__ ib,
                  const float* __restrict__ ab1,
                  const short* __restrict__ wp, int* __restrict__ owner,
                  short* __restrict__ ntab, float* __restrict__ out_nf,
                  float* __restrict__ npart, float* __restrict__ out_embed)
{
    __shared__ __align__(16) char smem[33792];
    __shared__ int sNd[64];

    const int tid = threadIdx.x;
    const int l = tid & 63, lr = l & 15, lq = l >> 4, n0 = (tid >> 6) * 32;
    const int kA = lq * 8, nc0 = n0 + lr, nc1 = n0 + 16 + lr;

    if (blockIdx.x < NBLK_NEIGH) {
        const int r0 = blockIdx.x * 64;
        const int nrows = (NI - r0 < 64) ? (NI - r0) : 64;

        for (int task = tid; task < 64 * 32; task += 256) {
            int row = task >> 5, c = task & 31;
            if (row < nrows) {
                const float* src = i_weight + (size_t)(r0 + row) * DK + c * 8;
                float4 f0 = *(const float4*)src;
                float4 f1 = *(const float4*)(src + 4);
                short8 o;
                o[0]=f2b(f0.x); o[1]=f2b(f0.y); o[2]=f2b(f0.z); o[3]=f2b(f0.w);
                o[4]=f2b(f1.x); o[5]=f2b(f1.y); o[6]=f2b(f1.z); o[7]=f2b(f1.w);
                *reinterpret_cast<short8*>(smem + row * 528 + c * 16) = o;
            }
        }
        __syncthreads();

        const short* iWt = wp + OFF_IWT;
        f32x4 acc[4][2];
        #pragma unroll
        for (int m = 0; m < 4; ++m) { acc[m][0] = {0.f,0.f,0.f,0.f}; acc[m][1] = {0.f,0.f,0.f,0.f}; }
        #pragma unroll
        for (int ks = 0; ks < 8; ++ks) {
            int k = ks * 32 + kA;
            short8 w0 = *reinterpret_cast<const short8*>(iWt + nc0 * DK + k);
            short8 w1 = *reinterpret_cast<const short8*>(iWt + nc1 * DK + k);
            #pragma unroll
            for (int m = 0; m < 4; ++m) {
                short8 a = LDROW(smem, 528, m * 16 + lr, k);
                acc[m][0] = MFMA(a, w0, acc[m][0]);
                acc[m][1] = MFMA(a, w1, acc[m][1]);
            }
        }
        __syncthreads();
        {
            float ib0 = ib[nc0], ib1 = ib[nc1];
            #pragma unroll
            for (int m = 0; m < 4; ++m)
                #pragma unroll
                for (int nt = 0; nt < 2; ++nt) {
                    int n = nt ? nc1 : nc0;
                    float bv = nt ? ib1 : ib0;
                    #pragma unroll
                    for (int r = 0; r < 4; ++r) {
                        int row = m * 16 + lq * 4 + r;
                        *reinterpret_cast<short*>(smem + row * 264 + n * 2)
                            = (short)f2b(acc[m][nt][r] + bv);
                    }
                }
        }
        __syncthreads();
        for (int g = tid; g < nrows * 16; g += 256) {
            int row = g >> 4, s = g & 15;
            short8 v = *reinterpret_cast<const short8*>(smem + row * 264 + s * 16);
            *reinterpret_cast<short8*>(ntab + (size_t)(r0 + row) * EN + s * 8) = v;
        }
    } else {
        const int bblk = blockIdx.x - NBLK_NEIGH;
        const int r0 = bblk * 64;
        {
            int bq = bblk * 256 + tid;
            if (bq < BB) atomicMax(&owner[nodes[bq]], bq);
        }
        if (tid < 64) sNd[tid] = nodes[r0 + tid];
        __syncthreads();

        for (int task = tid; task < 64 * 32; task += 256) {
            int row = task >> 5, c = task & 31;
            const float* src = u_weight + (size_t)sNd[row] * DK + c * 8;
            float4 f0 = *(const float4*)src;
            float4 f1 = *(const float4*)(src + 4);
            short8 o;
            o[0]=f2b(f0.x); o[1]=f2b(f0.y); o[2]=f2b(f0.z); o[3]=f2b(f0.w);
            o[4]=f2b(f1.x); o[5]=f2b(f1.y); o[6]=f2b(f1.z); o[7]=f2b(f1.w);
            *reinterpret_cast<short8*>(smem + row * 528 + c * 16) = o;
        }
        __syncthreads();

        const short* uWt   = wp + OFF_UWT;
        const short* aW1Lt = wp + OFF_AW1LT;

        f32x4 acc[4][2];
        #pragma unroll
        for (int m = 0; m < 4; ++m) { acc[m][0] = {0.f,0.f,0.f,0.f}; acc[m][1] = {0.f,0.f,0.f,0.f}; }
        #pragma unroll
        for (int ks = 0; ks < 8; ++ks) {
            int k = ks * 32 + kA;
            short8 w0 = *reinterpret_cast<const short8*>(uWt + nc0 * DK + k);
            short8 w1 = *reinterpret_cast<const short8*>(uWt + nc1 * DK + k);
            #pragma unroll
            for (int m = 0; m < 4; ++m) {
                short8 a = LDROW(smem, 528, m * 16 + lr, k);
                acc[m][0] = MFMA(a, w0, acc[m][0]);
                acc[m][1] = MFMA(a, w1, acc[m][1]);
            }
        }
        __syncthreads();
        {
            float b0v = ub[nc0], b1v = ub[nc1];
            #pragma unroll
            for (int m = 0; m < 4; ++m)
                #pragma unroll
                for (int nt = 0; nt < 2; ++nt) {
                    int n = nt ? nc1 : nc0;
                    float bv = nt ? b1v : b0v;
                    #pragma unroll
                    for (int r = 0; r < 4; ++r) {
                        int row = m * 16 + lq * 4 + r;
                        float v = acc[m][nt][r] + bv;
                        out_nf[(size_t)(r0 + row) * EN + n] = v;
                        *reinterpret_cast<short*>(smem + row * 272 + n * 2) = (short)f2b(v);
                    }
                }
        }
        __syncthreads();

        f32x4 ap[4][2];
        #pragma unroll
        for (int m = 0; m < 4; ++m) { ap[m][0] = {0.f,0.f,0.f,0.f}; ap[m][1] = {0.f,0.f,0.f,0.f}; }
        #pragma unroll
        for (int ks = 0; ks < 4; ++ks) {
            int k = ks * 32 + kA;
            short8 w0 = *reinterpret_cast<const short8*>(aW1Lt + nc0 * EN + k);
            short8 w1 = *reinterpret_cast<const short8*>(aW1Lt + nc1 * EN + k);
            #pragma unroll
            for (int m = 0; m < 4; ++m) {
                short8 a = LDROW(smem, 272, m * 16 + lr, k);
                ap[m][0] = MFMA(a, w0, ap[m][0]);
                ap[m][1] = MFMA(a, w1, ap[m][1]);
            }
        }
        {
            float b0v = ab1[nc0], b1v = ab1[nc1];
            #pragma unroll
            for (int m = 0; m < 4; ++m)
                #pragma unroll
                for (int nt = 0; nt < 2; ++nt) {
                    int n = nt ? nc1 : nc0;
                    float bv = nt ? b1v : b0v;
                    #pragma unroll
                    for (int r = 0; r < 4; ++r) {
                        int row = m * 16 + lq * 4 + r;
                        npart[(size_t)(r0 + row) * EN + n] = ap[m][nt][r] + bv;
                    }
                }
        }
    }

    {
        float4* embed4 = (float4*)out_embed;
        const int n16 = NU * EN / 4;
        const int gsz = (NBLK_NEIGH + NBLK_NF) * 256;
        float4 z = {0.f, 0.f, 0.f, 0.f};
        for (int i = blockIdx.x * 256 + tid; i < n16; i += gsz) embed4[i] = z;
    }
}

// ---- K3: attn (R11 structure); gather via global_load_lds into linear 256B-stride sNg ----
__global__ __launch_bounds__(256, 3)
void attn_kernel(const int* __restrict__ nodes, const int* __restrict__ neigh_idx,
                 const float* __restrict__ ab2, const float* __restrict__ aW3,
                 const float* __restrict__ ab3, const short* __restrict__ wp,
                 const short* __restrict__ ntab, const float* __restrict__ npart,
                 const int* __restrict__ owner, float* __restrict__ out_embed)
{
    __shared__ __align__(16) char sNg[96 * 256];   // 24576 B, LINEAR (global_load_lds dest)
    __shared__ __align__(16) char sH1[96 * 272];   // 26112 B, padded stride (conflict-free reads)
    __shared__ float sLogP[4][96];                 //  1536 B  => 52224 B total -> 3 blocks/CU

    const int tid = threadIdx.x;
    const int b0  = blockIdx.x * GGA;
    const int l   = tid & 63, w = tid >> 6;
    const int lr  = l & 15, lq = l >> 4;
    const int n0  = w * 32;
    const int kA  = lq * 8, nc0 = n0 + lr, nc1 = n0 + 16 + lr;

    // ---- gather: 6 x global_load_lds per wave; each writes 4 rows (1024 B linear) ----
    {
        const int s = l & 15, q = l >> 4;
        #pragma unroll
        for (int j = 0; j < 6; ++j) {
            int row = j * 4 + q;
            int idx = neigh_idx[(b0 + w) * TT + row];
            const short* src = ntab + (size_t)idx * EN + s * 8;       // per-lane global addr
            char* ldsbase = sNg + (w * 24 + j * 4) * 256;             // wave-uniform base
            gload_lds16(src, ldsbase);
        }
    }
    __syncthreads();   // compiler drains vmcnt before barrier -> LDS valid

    const short* aW1Ut = wp + OFF_AW1UT;
    const short* aW2t  = wp + OFF_AW2T;

    // ---- h1 = relu(neighs @ aW1U + npart) ----
    f32x4 acc[6][2];
    #pragma unroll
    for (int m = 0; m < 6; ++m) { acc[m][0] = {0.f,0.f,0.f,0.f}; acc[m][1] = {0.f,0.f,0.f,0.f}; }
    #pragma unroll
    for (int ks = 0; ks < 4; ++ks) {
        int k = ks * 32 + kA;
        short8 w0 = *reinterpret_cast<const short8*>(aW1Ut + nc0 * EN + k);
        short8 w1 = *reinterpret_cast<const short8*>(aW1Ut + nc1 * EN + k);
        #pragma unroll
        for (int m = 0; m < 6; ++m) {
            short8 a = LDROW(sNg, 256, m * 16 + lr, k);
            acc[m][0] = MFMA(a, w0, acc[m][0]);
            acc[m][1] = MFMA(a, w1, acc[m][1]);
        }
    }
    #pragma unroll
    for (int m = 0; m < 6; ++m) {
        int g = (m == 0) ? 0 : (m == 1) ? ((lq < 2) ? 0 : 1)
              : (m == 2) ? 1 : (m == 3) ? 2 : (m == 4) ? ((lq < 2) ? 2 : 3) : 3;
        #pragma unroll
        for (int nt = 0; nt < 2; ++nt) {
            int n = nt ? nc1 : nc0;
            float np = npart[(size_t)(b0 + g) * EN + n];   // L1-hot (2 KB working set)
            float v0 = fmaxf(acc[m][nt][0] + np, 0.f);
            float v1 = fmaxf(acc[m][nt][1] + np, 0.f);
            float v2 = fmaxf(acc[m][nt][2] + np, 0.f);
            float v3 = fmaxf(acc[m][nt][3] + np, 0.f);
            unsigned int p01 = cvtpk_bf16(v0, v1);
            unsigned int p23 = cvtpk_bf16(v2, v3);
            char* base = sH1 + (m * 16 + lq * 4) * 272 + n * 2;
            *reinterpret_cast<short*>(base)       = (short)(p01 & 0xFFFF);
            *reinterpret_cast<short*>(base + 272) = (short)(p01 >> 16);
            *reinterpret_cast<short*>(base + 544) = (short)(p23 & 0xFFFF);
            *reinterpret_cast<short*>(base + 816) = (short)(p23 >> 16);
        }
    }
    __syncthreads();

    // ---- h2 = relu(h1 @ aW2 + ab2); logits reduced in-register ----
    #pragma unroll
    for (int m = 0; m < 6; ++m) { acc[m][0] = {0.f,0.f,0.f,0.f}; acc[m][1] = {0.f,0.f,0.f,0.f}; }
    #pragma unroll
    for (int ks = 0; ks < 4; ++ks) {
        int k = ks * 32 + kA;
        short8 w0 = *reinterpret_cast<const short8*>(aW2t + nc0 * EN + k);
        short8 w1 = *reinterpret_cast<const short8*>(aW2t + nc1 * EN + k);
        #pragma unroll
        for (int m = 0; m < 6; ++m) {
            short8 a = LDROW(sH1, 272, m * 16 + lr, k);
            acc[m][0] = MFMA(a, w0, acc[m][0]);
            acc[m][1] = MFMA(a, w1, acc[m][1]);
        }
    }
    {
        float b0v = ab2[nc0], b1v = ab2[nc1];
        float w3a = aW3[nc0], w3b = aW3[nc1];
        #pragma unroll
        for (int m = 0; m < 6; ++m) {
            float lp[4];
            #pragma unroll
            for (int r = 0; r < 4; ++r) {
                float v0 = fmaxf(acc[m][0][r] + b0v, 0.f);
                float v1 = fmaxf(acc[m][1][r] + b1v, 0.f);
                lp[r] = v0 * w3a + v1 * w3b;
            }
            #pragma unroll
            for (int r = 0; r < 4; ++r) {
                float v = lp[r];
                v += __shfl_xor(v, 1, 16);
                v += __shfl_xor(v, 2, 16);
                v += __shfl_xor(v, 4, 16);
                v += __shfl_xor(v, 8, 16);
                if (lr == 0) sLogP[w][m * 16 + lq * 4 + r] = v;
            }
        }
    }
    __syncthreads();

    // ---- per-wave softmax over T=24 for batch row b0+w ----
    float lg = -1e30f;
    if (l < TT)
        lg = sLogP[0][w * 24 + l] + sLogP[1][w * 24 + l]
           + sLogP[2][w * 24 + l] + sLogP[3][w * 24 + l] + ab3[0];
    float mx = lg;
    #pragma unroll
    for (int d = 32; d > 0; d >>= 1) mx = fmaxf(mx, __shfl_xor(mx, d, 64));
    float p = (l < TT) ? __expf(lg - mx) : 0.f;
    float s = p;
    #pragma unroll
    for (int d = 32; d > 0; d >>= 1) s += __shfl_xor(s, d, 64);
    float att = p / s;

    // ---- agg + scatter: lane l covers cols l and l+64 of batch row b0+w ----
    {
        float a0 = 0.f, a1 = 0.f;
        #pragma unroll
        for (int t = 0; t < TT; ++t) {
            float wt = __shfl(att, t, 64);
            const char* rbase = sNg + (w * 24 + t) * 256;
            a0 += wt * b2f(*reinterpret_cast<const unsigned short*>(rbase + l * 2));
            a1 += wt * b2f(*reinterpret_cast<const unsigned short*>(rbase + (l + 64) * 2));
        }
        int node = nodes[b0 + w];
        if (owner[node] == b0 + w) {
            out_embed[(size_t)node * EN + l]      = a0;
            out_embed[(size_t)node * EN + 64 + l] = a1;
        }
    }
}

extern "C" void kernel_launch(void* const* d_in, const int* in_sizes, int n_in,
                              void* d_out, int out_size, void* d_ws, size_t ws_size,
                              hipStream_t stream) {
    const int*   nodes     = (const int*)d_in[0];
    const int*   neigh_idx = (const int*)d_in[1];
    const float* u_weight  = (const float*)d_in[2];
    const float* i_weight  = (const float*)d_in[3];
    const float* uW  = (const float*)d_in[4];
    const float* ub  = (const float*)d_in[5];
    const float* iW  = (const float*)d_in[6];
    const float* ib  = (const float*)d_in[7];
    const float* aW1 = (const float*)d_in[8];
    const float* ab1 = (const float*)d_in[9];
    const float* aW2 = (const float*)d_in[10];
    const float* ab2 = (const float*)d_in[11];
    const float* aW3 = (const float*)d_in[12];
    const float* ab3 = (const float*)d_in[13];

    float* out_nf    = (float*)d_out;
    float* out_embed = out_nf + (size_t)BB * EN;

    char*  ws    = (char*)d_ws;
    short* wpack = (short*)(ws + WP_OFF);
    int*   owner = (int*)(ws + OWNER_OFF);
    short* ntab  = (short*)(ws + NTAB_OFF);
    float* npart = (float*)(ws + NPART_OFF);

    prep_kernel<<<NBLK_PACK + 32, 256, 0, stream>>>(nodes, uW, iW, aW1, aW2, wpack, owner);
    embed_kernel<<<NBLK_NEIGH + NBLK_NF, 256, 0, stream>>>(
        nodes, u_weight, i_weight, ub, ib, ab1, wpack, owner, ntab, out_nf, npart, out_embed);
    attn_kernel<<<ATTN_BLKS, 256, 0, stream>>>(nodes, neigh_idx, ab2, aW3, ab3,
                                               wpack, ntab, npart, owner, out_embed);
}

// Round 17
// 74.946 us; speedup vs baseline: 1.5721x; 1.0436x over previous
//
#include <hip/hip_runtime.h>
#include <math.h>

#define NU 100000
#define NI 50000
#define DK 256      // DU == DI
#define EN 128      // E
#define BB 8192
#define TT 24

typedef short short8 __attribute__((ext_vector_type(8)));
typedef float f32x4  __attribute__((ext_vector_type(4)));

// ---- d_ws layout (bytes) ----
#define WPACK_SHORTS 114688
#define WP_OFF     0
#define OWNER_OFF  229376                 // 100000 ints
#define NTAB_OFF   629376                 // 50000*128 bf16 = 12.8 MB
#define NPART_OFF  13429376               // 8192*128 f32  = 4 MB

// wpack element offsets (bf16 shorts, all [N][K] k-contiguous)
#define OFF_IWT   0        // 128x256
#define OFF_UWT   32768    // 128x256
#define OFF_AW1UT 65536    // 128x128 (aW1 rows 0..127   -> neigh part)
#define OFF_AW1LT 81920    // 128x128 (aW1 rows 128..255 -> node part)
#define OFF_AW2T  98304    // 128x128

#define NBLK_NEIGH 782     // ceil(NI/64)
#define NBLK_NF    128     // BB/64
#define NBLK_PACK  448     // WPACK_SHORTS/256
#define GGA 4              // batch rows per attn block
#define ATTN_BLKS  (BB / GGA)

__device__ __forceinline__ unsigned short f2b(float x) {
    unsigned int u = __float_as_uint(x);
    u = (u + 0x7FFFu + ((u >> 16) & 1u)) >> 16;   // RNE, finite inputs
    return (unsigned short)u;
}
__device__ __forceinline__ float b2f(unsigned short v) {
    return __uint_as_float(((unsigned int)v) << 16);
}
__device__ __forceinline__ unsigned int cvtpk_bf16(float lo, float hi) {
    unsigned int r;
    asm("v_cvt_pk_bf16_f32 %0, %1, %2" : "=v"(r) : "v"(lo), "v"(hi));
    return r;
}

#define MFMA(a, b, c) __builtin_amdgcn_mfma_f32_16x16x32_bf16((a), (b), (c), 0, 0, 0)
#define LDROW(buf, stride, row, k) \
    (*reinterpret_cast<const short8*>(reinterpret_cast<const char*>(buf) + (row) * (stride) + (k) * 2))

// ---- K1 (tiny): pack weights + owner reset ----
__global__ __launch_bounds__(256)
void prep_kernel(const int* __restrict__ nodes,
                 const float* __restrict__ uW, const float* __restrict__ iW,
                 const float* __restrict__ aW1, const float* __restrict__ aW2,
                 short* __restrict__ wp, int* __restrict__ owner)
{
    if (blockIdx.x < NBLK_PACK) {
        int i = blockIdx.x * 256 + threadIdx.x;
        float v;
        if (i < 32768)      { int j = i;         int n = j >> 8, k = j & 255; v = iW[k * EN + n]; }
        else if (i < 65536) { int j = i - 32768; int n = j >> 8, k = j & 255; v = uW[k * EN + n]; }
        else if (i < 81920) { int j = i - 65536; int n = j >> 7, k = j & 127; v = aW1[k * EN + n]; }
        else if (i < 98304) { int j = i - 81920; int n = j >> 7, k = j & 127; v = aW1[(128 + k) * EN + n]; }
        else                { int j = i - 98304; int n = j >> 7, k = j & 127; v = aW2[k * EN + n]; }
        wp[i] = (short)f2b(v);
    } else {
        int b = (blockIdx.x - NBLK_PACK) * 256 + threadIdx.x;
        if (b < BB) owner[nodes[b]] = -1;
    }
}

// ---- K2: union kernel: neighs table | nf/npart (+owner max) ; tail-zero of out_embed ----
__global__ __launch_bounds__(256, 4)
void embed_kernel(const int* __restrict__ nodes,
                  const float* __restrict__ u_weight, const float* __restrict__ i_weight,
                  const float* __restrict__ ub, const float* __restrict__ ib,
                  const float* __restrict__ ab1,
                  const short* __restrict__ wp, int* __restrict__ owner,
                  short* __restrict__ ntab, float* __restrict__ out_nf,
                  float* __restrict__ npart, float* __restrict__ out_embed)
{
    __shared__ __align__(16) char smem[33792];
    __shared__ int sNd[64];

    const int tid = threadIdx.x;
    const int l = tid & 63, lr = l & 15, lq = l >> 4, n0 = (tid >> 6) * 32;
    const int kA = lq * 8, nc0 = n0 + lr, nc1 = n0 + 16 + lr;

    if (blockIdx.x < NBLK_NEIGH) {
        const int r0 = blockIdx.x * 64;
        const int nrows = (NI - r0 < 64) ? (NI - r0) : 64;

        for (int task = tid; task < 64 * 32; task += 256) {
            int row = task >> 5, c = task & 31;
            if (row < nrows) {
                const float* src = i_weight + (size_t)(r0 + row) * DK + c * 8;
                float4 f0 = *(const float4*)src;
                float4 f1 = *(const float4*)(src + 4);
                short8 o;
                o[0]=f2b(f0.x); o[1]=f2b(f0.y); o[2]=f2b(f0.z); o[3]=f2b(f0.w);
                o[4]=f2b(f1.x); o[5]=f2b(f1.y); o[6]=f2b(f1.z); o[7]=f2b(f1.w);
                *reinterpret_cast<short8*>(smem + row * 528 + c * 16) = o;
            }
        }
        __syncthreads();

        const short* iWt = wp + OFF_IWT;
        f32x4 acc[4][2];
        #pragma unroll
        for (int m = 0; m < 4; ++m) { acc[m][0] = {0.f,0.f,0.f,0.f}; acc[m][1] = {0.f,0.f,0.f,0.f}; }
        #pragma unroll
        for (int ks = 0; ks < 8; ++ks) {
            int k = ks * 32 + kA;
            short8 w0 = *reinterpret_cast<const short8*>(iWt + nc0 * DK + k);
            short8 w1 = *reinterpret_cast<const short8*>(iWt + nc1 * DK + k);
            #pragma unroll
            for (int m = 0; m < 4; ++m) {
                short8 a = LDROW(smem, 528, m * 16 + lr, k);
                acc[m][0] = MFMA(a, w0, acc[m][0]);
                acc[m][1] = MFMA(a, w1, acc[m][1]);
            }
        }
        __syncthreads();
        {
            float ib0 = ib[nc0], ib1 = ib[nc1];
            #pragma unroll
            for (int m = 0; m < 4; ++m)
                #pragma unroll
                for (int nt = 0; nt < 2; ++nt) {
                    int n = nt ? nc1 : nc0;
                    float bv = nt ? ib1 : ib0;
                    #pragma unroll
                    for (int r = 0; r < 4; ++r) {
                        int row = m * 16 + lq * 4 + r;
                        *reinterpret_cast<short*>(smem + row * 264 + n * 2)
                            = (short)f2b(acc[m][nt][r] + bv);
                    }
                }
        }
        __syncthreads();
        for (int g = tid; g < nrows * 16; g += 256) {
            int row = g >> 4, s = g & 15;
            short8 v = *reinterpret_cast<const short8*>(smem + row * 264 + s * 16);
            *reinterpret_cast<short8*>(ntab + (size_t)(r0 + row) * EN + s * 8) = v;
        }
    } else {
        const int bblk = blockIdx.x - NBLK_NEIGH;
        const int r0 = bblk * 64;
        {
            int bq = bblk * 256 + tid;
            if (bq < BB) atomicMax(&owner[nodes[bq]], bq);
        }
        if (tid < 64) sNd[tid] = nodes[r0 + tid];
        __syncthreads();

        for (int task = tid; task < 64 * 32; task += 256) {
            int row = task >> 5, c = task & 31;
            const float* src = u_weight + (size_t)sNd[row] * DK + c * 8;
            float4 f0 = *(const float4*)src;
            float4 f1 = *(const float4*)(src + 4);
            short8 o;
            o[0]=f2b(f0.x); o[1]=f2b(f0.y); o[2]=f2b(f0.z); o[3]=f2b(f0.w);
            o[4]=f2b(f1.x); o[5]=f2b(f1.y); o[6]=f2b(f1.z); o[7]=f2b(f1.w);
            *reinterpret_cast<short8*>(smem + row * 528 + c * 16) = o;
        }
        __syncthreads();

        const short* uWt   = wp + OFF_UWT;
        const short* aW1Lt = wp + OFF_AW1LT;

        f32x4 acc[4][2];
        #pragma unroll
        for (int m = 0; m < 4; ++m) { acc[m][0] = {0.f,0.f,0.f,0.f}; acc[m][1] = {0.f,0.f,0.f,0.f}; }
        #pragma unroll
        for (int ks = 0; ks < 8; ++ks) {
            int k = ks * 32 + kA;
            short8 w0 = *reinterpret_cast<const short8*>(uWt + nc0 * DK + k);
            short8 w1 = *reinterpret_cast<const short8*>(uWt + nc1 * DK + k);
            #pragma unroll
            for (int m = 0; m < 4; ++m) {
                short8 a = LDROW(smem, 528, m * 16 + lr, k);
                acc[m][0] = MFMA(a, w0, acc[m][0]);
                acc[m][1] = MFMA(a, w1, acc[m][1]);
            }
        }
        __syncthreads();
        {
            float b0v = ub[nc0], b1v = ub[nc1];
            #pragma unroll
            for (int m = 0; m < 4; ++m)
                #pragma unroll
                for (int nt = 0; nt < 2; ++nt) {
                    int n = nt ? nc1 : nc0;
                    float bv = nt ? b1v : b0v;
                    #pragma unroll
                    for (int r = 0; r < 4; ++r) {
                        int row = m * 16 + lq * 4 + r;
                        float v = acc[m][nt][r] + bv;
                        out_nf[(size_t)(r0 + row) * EN + n] = v;
                        *reinterpret_cast<short*>(smem + row * 272 + n * 2) = (short)f2b(v);
                    }
                }
        }
        __syncthreads();

        f32x4 ap[4][2];
        #pragma unroll
        for (int m = 0; m < 4; ++m) { ap[m][0] = {0.f,0.f,0.f,0.f}; ap[m][1] = {0.f,0.f,0.f,0.f}; }
        #pragma unroll
        for (int ks = 0; ks < 4; ++ks) {
            int k = ks * 32 + kA;
            short8 w0 = *reinterpret_cast<const short8*>(aW1Lt + nc0 * EN + k);
            short8 w1 = *reinterpret_cast<const short8*>(aW1Lt + nc1 * EN + k);
            #pragma unroll
            for (int m = 0; m < 4; ++m) {
                short8 a = LDROW(smem, 272, m * 16 + lr, k);
                ap[m][0] = MFMA(a, w0, ap[m][0]);
                ap[m][1] = MFMA(a, w1, ap[m][1]);
            }
        }
        {
            float b0v = ab1[nc0], b1v = ab1[nc1];
            #pragma unroll
            for (int m = 0; m < 4; ++m)
                #pragma unroll
                for (int nt = 0; nt < 2; ++nt) {
                    int n = nt ? nc1 : nc0;
                    float bv = nt ? b1v : b0v;
                    #pragma unroll
                    for (int r = 0; r < 4; ++r) {
                        int row = m * 16 + lq * 4 + r;
                        npart[(size_t)(r0 + row) * EN + n] = ap[m][nt][r] + bv;
                    }
                }
        }
    }

    {
        float4* embed4 = (float4*)out_embed;
        const int n16 = NU * EN / 4;
        const int gsz = (NBLK_NEIGH + NBLK_NF) * 256;
        float4 z = {0.f, 0.f, 0.f, 0.f};
        for (int i = blockIdx.x * 256 + tid; i < n16; i += gsz) embed4[i] = z;
    }
}

// ---- K3: attn (R8 structure), LDS trimmed to 53760 B -> 3 blocks/CU ----
__global__ __launch_bounds__(256, 3)
void attn_kernel(const int* __restrict__ nodes, const int* __restrict__ neigh_idx,
                 const float* __restrict__ ab2, const float* __restrict__ aW3,
                 const float* __restrict__ ab3, const short* __restrict__ wp,
                 const short* __restrict__ ntab, const float* __restrict__ npart,
                 const int* __restrict__ owner, float* __restrict__ out_embed)
{
    __shared__ __align__(16) short sNg[96 * 136];  // 26112 B
    __shared__ __align__(16) short sH1[96 * 136];  // 26112 B
    __shared__ float sLogP[4][96];                 //  1536 B  => total 53760 B

    const int tid = threadIdx.x;
    const int b0  = blockIdx.x * GGA;
    const int l   = tid & 63, w = tid >> 6;
    const int lr  = l & 15, lq = l >> 4;
    const int n0  = w * 32;
    const int kA  = lq * 8, nc0 = n0 + lr, nc1 = n0 + 16 + lr;

    // gather: wave w stages its own 24 neighbor rows (256B bf16 each)
    #pragma unroll
    for (int j = 0; j < 6; ++j) {
        int task = j * 64 + l;
        int trow = task >> 4, s = task & 15;
        int idx = neigh_idx[(b0 + w) * TT + trow];
        short8 v = *reinterpret_cast<const short8*>(ntab + (size_t)idx * EN + s * 8);
        *reinterpret_cast<short8*>(reinterpret_cast<char*>(sNg) + (w * 24 + trow) * 272 + s * 16) = v;
    }
    __syncthreads();

    const short* aW1Ut = wp + OFF_AW1UT;
    const short* aW2t  = wp + OFF_AW2T;

    // ---- h1 = relu(neighs @ aW1U + npart) ----
    f32x4 acc[6][2];
    #pragma unroll
    for (int m = 0; m < 6; ++m) { acc[m][0] = {0.f,0.f,0.f,0.f}; acc[m][1] = {0.f,0.f,0.f,0.f}; }
    #pragma unroll
    for (int ks = 0; ks < 4; ++ks) {
        int k = ks * 32 + kA;
        short8 w0 = *reinterpret_cast<const short8*>(aW1Ut + nc0 * EN + k);
        short8 w1 = *reinterpret_cast<const short8*>(aW1Ut + nc1 * EN + k);
        #pragma unroll
        for (int m = 0; m < 6; ++m) {
            short8 a = LDROW(sNg, 272, m * 16 + lr, k);
            acc[m][0] = MFMA(a, w0, acc[m][0]);
            acc[m][1] = MFMA(a, w1, acc[m][1]);
        }
    }
    #pragma unroll
    for (int m = 0; m < 6; ++m) {
        int g = (m == 0) ? 0 : (m == 1) ? ((lq < 2) ? 0 : 1)
              : (m == 2) ? 1 : (m == 3) ? 2 : (m == 4) ? ((lq < 2) ? 2 : 3) : 3;
        #pragma unroll
        for (int nt = 0; nt < 2; ++nt) {
            int n = nt ? nc1 : nc0;
            float np = npart[(size_t)(b0 + g) * EN + n];   // L1-hot (2 KB working set)
            float v0 = fmaxf(acc[m][nt][0] + np, 0.f);
            float v1 = fmaxf(acc[m][nt][1] + np, 0.f);
            float v2 = fmaxf(acc[m][nt][2] + np, 0.f);
            float v3 = fmaxf(acc[m][nt][3] + np, 0.f);
            unsigned int p01 = cvtpk_bf16(v0, v1);
            unsigned int p23 = cvtpk_bf16(v2, v3);
            char* base = reinterpret_cast<char*>(sH1) + (m * 16 + lq * 4) * 272 + n * 2;
            *reinterpret_cast<short*>(base)       = (short)(p01 & 0xFFFF);
            *reinterpret_cast<short*>(base + 272) = (short)(p01 >> 16);
            *reinterpret_cast<short*>(base + 544) = (short)(p23 & 0xFFFF);
            *reinterpret_cast<short*>(base + 816) = (short)(p23 >> 16);
        }
    }
    __syncthreads();

    // ---- h2 = relu(h1 @ aW2 + ab2); logits reduced in-register ----
    #pragma unroll
    for (int m = 0; m < 6; ++m) { acc[m][0] = {0.f,0.f,0.f,0.f}; acc[m][1] = {0.f,0.f,0.f,0.f}; }
    #pragma unroll
    for (int ks = 0; ks < 4; ++ks) {
        int k = ks * 32 + kA;
        short8 w0 = *reinterpret_cast<const short8*>(aW2t + nc0 * EN + k);
        short8 w1 = *reinterpret_cast<const short8*>(aW2t + nc1 * EN + k);
        #pragma unroll
        for (int m = 0; m < 6; ++m) {
            short8 a = LDROW(sH1, 272, m * 16 + lr, k);
            acc[m][0] = MFMA(a, w0, acc[m][0]);
            acc[m][1] = MFMA(a, w1, acc[m][1]);
        }
    }
    {
        float b0v = ab2[nc0], b1v = ab2[nc1];
        float w3a = aW3[nc0], w3b = aW3[nc1];
        #pragma unroll
        for (int m = 0; m < 6; ++m) {
            float lp[4];
            #pragma unroll
            for (int r = 0; r < 4; ++r) {
                float v0 = fmaxf(acc[m][0][r] + b0v, 0.f);
                float v1 = fmaxf(acc[m][1][r] + b1v, 0.f);
                lp[r] = v0 * w3a + v1 * w3b;
            }
            #pragma unroll
            for (int r = 0; r < 4; ++r) {
                float v = lp[r];
                v += __shfl_xor(v, 1, 16);
                v += __shfl_xor(v, 2, 16);
                v += __shfl_xor(v, 4, 16);
                v += __shfl_xor(v, 8, 16);
                if (lr == 0) sLogP[w][m * 16 + lq * 4 + r] = v;
            }
        }
    }
    __syncthreads();

    // ---- per-wave softmax over T=24 for batch row b0+w ----
    float lg = -1e30f;
    if (l < TT)
        lg = sLogP[0][w * 24 + l] + sLogP[1][w * 24 + l]
           + sLogP[2][w * 24 + l] + sLogP[3][w * 24 + l] + ab3[0];
    float mx = lg;
    #pragma unroll
    for (int d = 32; d > 0; d >>= 1) mx = fmaxf(mx, __shfl_xor(mx, d, 64));
    float p = (l < TT) ? __expf(lg - mx) : 0.f;
    float s = p;
    #pragma unroll
    for (int d = 32; d > 0; d >>= 1) s += __shfl_xor(s, d, 64);
    float att = p / s;

    // ---- agg + scatter: lane l covers cols l and l+64 of batch row b0+w ----
    {
        float a0 = 0.f, a1 = 0.f;
        #pragma unroll
        for (int t = 0; t < TT; ++t) {
            float wt = __shfl(att, t, 64);
            const char* rbase = reinterpret_cast<const char*>(sNg) + (w * 24 + t) * 272;
            a0 += wt * b2f(*reinterpret_cast<const unsigned short*>(rbase + l * 2));
            a1 += wt * b2f(*reinterpret_cast<const unsigned short*>(rbase + (l + 64) * 2));
        }
        int node = nodes[b0 + w];
        if (owner[node] == b0 + w) {
            out_embed[(size_t)node * EN + l]      = a0;
            out_embed[(size_t)node * EN + 64 + l] = a1;
        }
    }
}

extern "C" void kernel_launch(void* const* d_in, const int* in_sizes, int n_in,
                              void* d_out, int out_size, void* d_ws, size_t ws_size,
                              hipStream_t stream) {
    const int*   nodes     = (const int*)d_in[0];
    const int*   neigh_idx = (const int*)d_in[1];
    const float* u_weight  = (const float*)d_in[2];
    const float* i_weight  = (const float*)d_in[3];
    const float* uW  = (const float*)d_in[4];
    const float* ub  = (const float*)d_in[5];
    const float* iW  = (const float*)d_in[6];
    const float* ib  = (const float*)d_in[7];
    const float* aW1 = (const float*)d_in[8];
    const float* ab1 = (const float*)d_in[9];
    const float* aW2 = (const float*)d_in[10];
    const float* ab2 = (const float*)d_in[11];
    const float* aW3 = (const float*)d_in[12];
    const float* ab3 = (const float*)d_in[13];

    float* out_nf    = (float*)d_out;
    float* out_embed = out_nf + (size_t)BB * EN;

    char*  ws    = (char*)d_ws;
    short* wpack = (short*)(ws + WP_OFF);
    int*   owner = (int*)(ws + OWNER_OFF);
    short* ntab  = (short*)(ws + NTAB_OFF);
    float* npart = (float*)(ws + NPART_OFF);

    prep_kernel<<<NBLK_PACK + 32, 256, 0, stream>>>(nodes, uW, iW, aW1, aW2, wpack, owner);
    embed_kernel<<<NBLK_NEIGH + NBLK_NF, 256, 0, stream>>>(
        nodes, u_weight, i_weight, ub, ib, ab1, wpack, owner, ntab, out_nf, npart, out_embed);
    attn_kernel<<<ATTN_BLKS, 256, 0, stream>>>(nodes, neigh_idx, ab2, aW3, ab3,
                                               wpack, ntab, npart, owner, out_embed);
}